// Round 2
// baseline (351.226 us; speedup 1.0000x reference)
//
#include <hip/hip_runtime.h>
#include <math.h>

#define BROWS 65536
#define LLEN  1024
#define KW    16
#define NPOS  (LLEN - KW + 1)   // 1009 valid conv outputs
#define ROWS_PER_BLOCK 4

__global__ __launch_bounds__(256) void conv_pool_classify(
    const float* __restrict__ x,       // (B, 1, L)
    const float* __restrict__ w,       // (1, 1, K)
    const float* __restrict__ bias,    // (1,)
    const float* __restrict__ ranges,  // (4, 2) row-major: [lo0,hi0,lo1,hi1,...]
    int* __restrict__ out)             // (B,1,1) labels as int32
{
    const int lane = threadIdx.x & 63;
    const int waveInBlock = threadIdx.x >> 6;
    const int row = blockIdx.x * ROWS_PER_BLOCK + waveInBlock;
    const float* __restrict__ xr = x + (size_t)row * LLEN;

    // ---- load filter (lane-uniform -> scalar loads) ----
    float wv[KW];
#pragma unroll
    for (int k = 0; k < KW; ++k) wv[k] = w[k];

    // ---- load own 16 floats (one 64B line) + neighbor's 16 (L1 hits) ----
    float xv[32];
    const int own = 16 * lane;
    const int nb  = (lane < 63) ? own + 16 : own;  // clamp: lane 63 never uses it validly
#pragma unroll
    for (int j = 0; j < 4; ++j)
        *(float4*)(&xv[4 * j]) = *(const float4*)(xr + own + 4 * j);
#pragma unroll
    for (int j = 0; j < 4; ++j)
        *(float4*)(&xv[16 + 4 * j]) = *(const float4*)(xr + nb + 4 * j);

    // ---- 16 conv outputs per lane, running max, tail predicated ----
    float vmax = -INFINITY;
#pragma unroll
    for (int p = 0; p < KW; ++p) {
        float acc = 0.0f;
#pragma unroll
        for (int k = 0; k < KW; ++k) acc = fmaf(xv[p + k], wv[k], acc);
        const bool valid = (own + p) < NPOS;   // only lane 63 has invalid p>0
        vmax = valid ? fmaxf(vmax, acc) : vmax;
    }

    // ---- wave-wide max reduction (64 lanes) ----
#pragma unroll
    for (int off = 32; off > 0; off >>= 1)
        vmax = fmaxf(vmax, __shfl_xor(vmax, off, 64));

    // ---- lane 0: bias + relu + classify + store ----
    if (lane == 0) {
        const float v = fmaxf(vmax + bias[0], 0.0f);

        int label = -1;
#pragma unroll
        for (int j = 0; j < 4; ++j) {
            const float lo = ranges[2 * j];
            const float hi = ranges[2 * j + 1];
            if (label < 0 && v >= lo && v <= hi) label = j;  // first match
        }
        if (label < 0) {
            // fallback: argmin_j sqrt(v*v + flat_bounds[j]) // 2, first-min tie rule
            float best = INFINITY;
            int bj = 0;
#pragma unroll
            for (int j = 0; j < 8; ++j) {
                const float d = sqrtf(v * v + ranges[j]);
                if (d < best) { best = d; bj = j; }
            }
            label = bj >> 1;
        }
        out[row] = label;
    }
}

extern "C" void kernel_launch(void* const* d_in, const int* in_sizes, int n_in,
                              void* d_out, int out_size, void* d_ws, size_t ws_size,
                              hipStream_t stream) {
    const float* x      = (const float*)d_in[0];
    const float* w      = (const float*)d_in[1];
    const float* bias   = (const float*)d_in[2];
    const float* ranges = (const float*)d_in[3];
    int* out = (int*)d_out;

    dim3 grid(BROWS / ROWS_PER_BLOCK);  // 16384 blocks, 4 waves each = 1 row/wave
    dim3 block(256);
    conv_pool_classify<<<grid, block, 0, stream>>>(x, w, bias, ranges, out);
}